// Round 5
// baseline (264.720 us; speedup 1.0000x reference)
//
#include <hip/hip_runtime.h>
#include <hip/hip_cooperative_groups.h>
namespace cg = cooperative_groups;

#define B_   32
#define H_   16
#define L_   577
#define D_   1024
#define CK   64
#define LP   576
#define DOM  54
#define NSEL 55
#define NR   522
#define CTX  10
#define NMERGE 512
#define NBLK 512
#define NTHR 256
#define SLICES 4

// remain-list position for merge index m: p = m + min(m/51,9) + 1
__device__ __forceinline__ int remain_pos(int m) {
    int k = m / 51; if (k > 9) k = 9;
    return m + k + 1;
}

struct WS {
    float dot[B_ * LP];          // fused: metric.text dot | fallback: Sd
    float ss[B_ * LP];           // fused: metric sumsq    | fallback: cos
    int   dom_idx[B_ * NSEL];
    int   rem_tok[B_ * NR];
    int   bucket_toks[B_ * CTX * NMERGE];
    int   bucket_cnt[B_ * CTX];
    float partial[(size_t)B_ * CTX * SLICES * D_];
};

// ===================== fused cooperative kernel =====================
__global__ __launch_bounds__(NTHR, 2) void fused(
    const float* __restrict__ attn, const float* __restrict__ hidden,
    const float* __restrict__ metric, const float* __restrict__ text,
    float* __restrict__ out, WS* __restrict__ ws)
{
    cg::grid_group grid = cg::this_grid();
    const int tid = threadIdx.x;
    const int bid = blockIdx.x;
    const int wv = tid >> 6, lane = tid & 63;

    __shared__ float sc[LP];
    __shared__ int   rem_s[NR];
    __shared__ float tg[CTX * CK];
    __shared__ float tinv[CTX];
    __shared__ unsigned long long smask[9];
    __shared__ unsigned long long bmask[8][CTX];
    __shared__ float red[8];
    __shared__ float bc[2];
    __shared__ float sh_invtn;
    __shared__ int   toks_lds[NMERGE];

    // ---------- phase 1: per-(b,j) metric dot & sumsq (wave-per-item) ----------
    {
        int gw = bid * 4 + wv;                       // 2048 global waves
        for (int it = gw; it < B_ * LP; it += NBLK * 4) {
            int b = it / LP, j = it - b * LP;
            float m = metric[((size_t)(b * L_ + 1 + j)) * CK + lane];
            float t = text[b * CK + lane];
            float d = m * t, s2 = m * m;
            for (int o = 32; o; o >>= 1) { d += __shfl_xor(d, o); s2 += __shfl_xor(s2, o); }
            if (lane == 0) { ws->dot[it] = d; ws->ss[it] = s2; }
        }
    }
    grid.sync();

    // ---------- phase 2: per-batch z-score, top-54, lists, assignment ----------
    if (bid < B_) {
        const int b = bid;
        if (tid < 64) {
            float t = text[b * CK + tid];
            float s2 = t * t;
            for (int o = 32; o; o >>= 1) s2 += __shfl_xor(s2, o);
            if (tid == 0) sh_invtn = 1.f / (sqrtf(s2) + 1e-12f);
        }
        __syncthreads();
        const float inv_tn = sh_invtn;

        float Sdv[3], csv[3];
        float sumS = 0.f, sumC = 0.f;
        #pragma unroll
        for (int s = 0; s < 3; ++s) {
            int j = tid + 256 * s;
            Sdv[s] = 0.f; csv[s] = 0.f;
            if (j < LP) {
                float Sd = 0.f;
                size_t base = (size_t)b * H_ * L_ * L_ + 1 + j;
                #pragma unroll
                for (int h = 0; h < H_; ++h) Sd += attn[base + (size_t)h * L_ * L_];
                float cs = ws->dot[b * LP + j] / (sqrtf(ws->ss[b * LP + j]) + 1e-12f) * inv_tn;
                Sdv[s] = Sd; csv[s] = cs;
                sumS += Sd; sumC += cs;
            }
        }
        {
            float a = sumS, c2 = sumC;
            for (int o = 32; o; o >>= 1) { a += __shfl_xor(a, o); c2 += __shfl_xor(c2, o); }
            if (lane == 0) { red[wv] = a; red[4 + wv] = c2; }
            __syncthreads();
            if (tid == 0) { bc[0] = red[0]+red[1]+red[2]+red[3]; bc[1] = red[4]+red[5]+red[6]+red[7]; }
            __syncthreads();
        }
        float mS = bc[0] * (1.f / LP), mC = bc[1] * (1.f / LP);
        __syncthreads();
        float s2S = 0.f, s2C = 0.f;
        #pragma unroll
        for (int s = 0; s < 3; ++s) {
            int j = tid + 256 * s;
            if (j < LP) {
                float dS = Sdv[s] - mS, dC = csv[s] - mC;
                s2S += dS * dS; s2C += dC * dC;
            }
        }
        {
            float a = s2S, c2 = s2C;
            for (int o = 32; o; o >>= 1) { a += __shfl_xor(a, o); c2 += __shfl_xor(c2, o); }
            if (lane == 0) { red[wv] = a; red[4 + wv] = c2; }
            __syncthreads();
            if (tid == 0) { bc[0] = red[0]+red[1]+red[2]+red[3]; bc[1] = red[4]+red[5]+red[6]+red[7]; }
            __syncthreads();
        }
        float izS = 0.5f / (sqrtf(bc[0] * (1.f / (LP - 1))) + 1e-6f);
        float izC = 0.5f / (sqrtf(bc[1] * (1.f / (LP - 1))) + 1e-6f);

        #pragma unroll
        for (int s = 0; s < 3; ++s) {
            int j = tid + 256 * s;
            if (j < LP) sc[j] = (Sdv[s] - mS) * izS + (csv[s] - mC) * izC;
        }
        __syncthreads();

        bool selv[3];
        #pragma unroll
        for (int s = 0; s < 3; ++s) {
            int j = tid + 256 * s;
            bool sel = false;
            if (j < LP) {
                float score = sc[j];
                int rank = 0;
                for (int k = 0; k < LP; ++k) {
                    float v = sc[k];
                    rank += (v > score) || (v == score && k < j);
                }
                sel = rank < DOM;
            }
            selv[s] = sel;
            unsigned long long m = __ballot(sel);
            int word = 4 * s + wv;
            if (word < 9 && lane == 0) smask[word] = m;
        }
        __syncthreads();
        #pragma unroll
        for (int s = 0; s < 3; ++s) {
            int j = tid + 256 * s;
            if (j < LP) {
                int word = j >> 6;
                int pre = 0;
                for (int w2 = 0; w2 < word; ++w2) pre += __popcll(smask[w2]);
                pre += __popcll(smask[word] & ((1ull << lane) - 1ull));
                if (selv[s]) ws->dom_idx[b * NSEL + 1 + pre] = j + 1;
                else { rem_s[j - pre] = j + 1; ws->rem_tok[b * NR + (j - pre)] = j + 1; }
            }
        }
        if (tid == 0) ws->dom_idx[b * NSEL] = 0;
        __syncthreads();

        for (int i = tid; i < CTX * CK; i += 256) {
            int k = i >> 6, c = i & 63;
            tg[i] = metric[((size_t)(b * L_ + rem_s[52 * k])) * CK + c];
        }
        __syncthreads();
        if (tid < CTX) {
            float s2 = 0.f;
            for (int c = 0; c < CK; ++c) { float t = tg[tid * CK + c]; s2 += t * t; }
            tinv[tid] = 1.f / (sqrtf(s2) + 1e-12f);
        }
        __syncthreads();

        int bk2[2], tok2[2];
        #pragma unroll
        for (int s = 0; s < 2; ++s) {
            int m = tid + 256 * s;
            int tok = rem_s[remain_pos(m)];
            const float4* row = (const float4*)&metric[((size_t)(b * L_ + tok)) * CK];
            float4 r[16];
            #pragma unroll
            for (int c4 = 0; c4 < 16; ++c4) r[c4] = row[c4];
            float best = -1e30f; int bk = 0;
            #pragma unroll
            for (int k = 0; k < CTX; ++k) {
                float d = 0.f;
                #pragma unroll
                for (int c4 = 0; c4 < 16; ++c4) {
                    float4 v = r[c4];
                    d += v.x * tg[k*CK + c4*4+0] + v.y * tg[k*CK + c4*4+1] +
                         v.z * tg[k*CK + c4*4+2] + v.w * tg[k*CK + c4*4+3];
                }
                d *= tinv[k];
                if (d > best) { best = d; bk = k; }
            }
            bk2[s] = bk; tok2[s] = tok;
            #pragma unroll
            for (int k = 0; k < CTX; ++k) {
                unsigned long long mk = __ballot(bk == k);
                if (lane == 0) bmask[4 * s + wv][k] = mk;
            }
        }
        __syncthreads();
        #pragma unroll
        for (int s = 0; s < 2; ++s) {
            int word = 4 * s + wv;
            int bk = bk2[s];
            int pos = 0;
            for (int w2 = 0; w2 < word; ++w2) pos += __popcll(bmask[w2][bk]);
            pos += __popcll(bmask[word][bk] & ((1ull << lane) - 1ull));
            ws->bucket_toks[(b * CTX + bk) * NMERGE + pos] = tok2[s];
        }
        if (tid < CTX) {
            int c = 0;
            #pragma unroll
            for (int w2 = 0; w2 < 8; ++w2) c += __popcll(bmask[w2][tid]);
            ws->bucket_cnt[b * CTX + tid] = c;
        }
    }
    grid.sync();

    // ---------- phase 3a: balanced bucket partial sums ----------
    for (int t = bid; t < B_ * CTX * SLICES; t += NBLK) {
        int b = t / (CTX * SLICES); int rr = t - b * CTX * SLICES;
        int k = rr / SLICES, s = rr - k * SLICES;
        int cnt = ws->bucket_cnt[b * CTX + k];
        const int* bt = &ws->bucket_toks[(b * CTX + k) * NMERGE];
        for (int i = tid; i < cnt; i += NTHR) toks_lds[i] = bt[i];
        __syncthreads();
        const float4* hb = (const float4*)&hidden[(size_t)b * L_ * D_];
        float4 a0 = make_float4(0.f, 0.f, 0.f, 0.f), a1 = a0;
        int i = s;
        for (; i + 4 < cnt; i += 8) {
            float4 v0 = hb[(size_t)toks_lds[i] * 256 + tid];
            float4 v1 = hb[(size_t)toks_lds[i + 4] * 256 + tid];
            a0.x += v0.x; a0.y += v0.y; a0.z += v0.z; a0.w += v0.w;
            a1.x += v1.x; a1.y += v1.y; a1.z += v1.z; a1.w += v1.w;
        }
        for (; i < cnt; i += 4) {
            float4 v = hb[(size_t)toks_lds[i] * 256 + tid];
            a0.x += v.x; a0.y += v.y; a0.z += v.z; a0.w += v.w;
        }
        float4 p;
        p.x = a0.x + a1.x; p.y = a0.y + a1.y; p.z = a0.z + a1.z; p.w = a0.w + a1.w;
        ((float4*)&ws->partial[((size_t)(b * CTX + k) * SLICES + s) * D_])[tid] = p;
        __syncthreads();
    }
    grid.sync();

    // ---------- phase 3b: write output rows ----------
    for (int row = bid; row < B_ * 65; row += NBLK) {
        int b = row / 65, r = row - b * 65;
        float4* dst = (float4*)&out[(size_t)row * D_];
        const float4* hb = (const float4*)&hidden[(size_t)b * L_ * D_];
        if (r < NSEL) {
            int tok = ws->dom_idx[b * NSEL + r];
            dst[tid] = hb[(size_t)tok * 256 + tid];
        } else {
            int k = r - NSEL;
            int cnt = ws->bucket_cnt[b * CTX + k];
            int tgt = ws->rem_tok[b * NR + 52 * k];
            const float4* pp = (const float4*)&ws->partial[(size_t)(b * CTX + k) * SLICES * D_];
            float4 p0 = pp[tid], p1 = pp[256 + tid], p2 = pp[512 + tid], p3 = pp[768 + tid];
            float4 bv = hb[(size_t)tgt * 256 + tid];
            float inv = 1.f / fmaxf((float)cnt, 1.f);
            float4 o;
            o.x = bv.x + ((p0.x + p1.x) + (p2.x + p3.x)) * inv;
            o.y = bv.y + ((p0.y + p1.y) + (p2.y + p3.y)) * inv;
            o.z = bv.z + ((p0.z + p1.z) + (p2.z + p3.z)) * inv;
            o.w = bv.w + ((p0.w + p1.w) + (p2.w + p3.w)) * inv;
            dst[tid] = o;
        }
    }
}

// ===================== fallback path (proven R3 kernels) =====================
__global__ __launch_bounds__(256) void k_raw(
    const float* __restrict__ attn, const float* __restrict__ metric,
    const float* __restrict__ text, float* __restrict__ Sd_arr,
    float* __restrict__ cos_arr)
{
    const int t = blockIdx.x * 256 + threadIdx.x;
    const int b = t / LP, j = t - b * LP;
    float Sd = 0.f;
    {
        size_t base = (size_t)b * H_ * L_ * L_ + (size_t)(1 + j);
        #pragma unroll
        for (int h = 0; h < H_; ++h) Sd += attn[base + (size_t)h * L_ * L_];
    }
    const float4* row  = (const float4*)&metric[((size_t)(b * L_ + 1 + j)) * CK];
    const float4* trow = (const float4*)&text[(size_t)b * CK];
    float dot = 0.f, ss = 0.f, ts = 0.f;
    #pragma unroll
    for (int c4 = 0; c4 < CK / 4; ++c4) {
        float4 v = row[c4]; float4 tv = trow[c4];
        ss  += v.x*v.x + v.y*v.y + v.z*v.z + v.w*v.w;
        ts  += tv.x*tv.x + tv.y*tv.y + tv.z*tv.z + tv.w*tv.w;
        dot += v.x*tv.x + v.y*tv.y + v.z*tv.z + v.w*tv.w;
    }
    Sd_arr[t] = Sd;
    cos_arr[t] = dot / (sqrtf(ss) + 1e-12f) / (sqrtf(ts) + 1e-12f);
}

__device__ float block_sum576(float v) {
    __shared__ float red9[9];
    __shared__ float tot;
    for (int o = 32; o; o >>= 1) v += __shfl_xor(v, o);
    if ((threadIdx.x & 63) == 0) red9[threadIdx.x >> 6] = v;
    __syncthreads();
    if (threadIdx.x < 16) {
        float s = (threadIdx.x < 9) ? red9[threadIdx.x] : 0.f;
        for (int o = 8; o; o >>= 1) s += __shfl_xor(s, o);
        if (threadIdx.x == 0) tot = s;
    }
    __syncthreads();
    float r = tot;
    __syncthreads();
    return r;
}

__global__ __launch_bounds__(576) void k_select(
    const float* __restrict__ Sd_arr, const float* __restrict__ cos_arr,
    const float* __restrict__ metric,
    int* __restrict__ dom_idx, int* __restrict__ rem_tok,
    int* __restrict__ bucket_toks, int* __restrict__ bucket_cnt)
{
    const int b = blockIdx.x;
    const int j = threadIdx.x;
    __shared__ float sc[LP];
    __shared__ unsigned long long smask[9];
    __shared__ int   rem_s[NR];
    __shared__ float tg[CTX * CK];
    __shared__ float tinv[CTX];
    __shared__ unsigned long long bmask[8][CTX];

    float Sd   = Sd_arr[b * LP + j];
    float cosv = cos_arr[b * LP + j];
    float mS = block_sum576(Sd)   * (1.f / LP);
    float dS = Sd - mS;
    float vS = block_sum576(dS * dS) * (1.f / (LP - 1));
    float mC = block_sum576(cosv) * (1.f / LP);
    float dC = cosv - mC;
    float vC = block_sum576(dC * dC) * (1.f / (LP - 1));
    float score = 0.5f * dS / (sqrtf(vS) + 1e-6f) + 0.5f * dC / (sqrtf(vC) + 1e-6f);
    sc[j] = score;
    __syncthreads();
    int rank = 0;
    for (int k = 0; k < LP; ++k) {
        float s = sc[k];
        rank += (s > score) || (s == score && k < j);
    }
    bool selj = (rank < DOM);
    const int w = j >> 6, lane = j & 63;
    unsigned long long m = __ballot(selj);
    if (lane == 0) smask[w] = m;
    __syncthreads();
    int pre = 0;
    for (int ww = 0; ww < w; ++ww) pre += __popcll(smask[ww]);
    pre += __popcll(smask[w] & ((1ull << lane) - 1ull));
    if (j == 0) dom_idx[b * NSEL] = 0;
    if (selj) dom_idx[b * NSEL + 1 + pre] = j + 1;
    else { rem_s[j - pre] = j + 1; rem_tok[b * NR + (j - pre)] = j + 1; }
    __syncthreads();
    for (int i = j; i < CTX * CK; i += 576) {
        int k = i >> 6, c = i & 63;
        tg[i] = metric[((size_t)(b * L_ + rem_s[52 * k])) * CK + c];
    }
    __syncthreads();
    if (j < CTX) {
        float s = 0.f;
        for (int c = 0; c < CK; ++c) { float t = tg[j * CK + c]; s += t * t; }
        tinv[j] = 1.f / (sqrtf(s) + 1e-12f);
    }
    __syncthreads();
    if (j < NMERGE) {
        const int tok = rem_s[remain_pos(j)];
        const float4* mrow = (const float4*)&metric[((size_t)(b * L_ + tok)) * CK];
        float4 r[16];
        #pragma unroll
        for (int c4 = 0; c4 < 16; ++c4) r[c4] = mrow[c4];
        float best = -1e30f; int bk = 0;
        #pragma unroll
        for (int k = 0; k < CTX; ++k) {
            float d = 0.f;
            #pragma unroll
            for (int c4 = 0; c4 < 16; ++c4) {
                float4 v = r[c4];
                d += v.x * tg[k*CK + c4*4+0] + v.y * tg[k*CK + c4*4+1] +
                     v.z * tg[k*CK + c4*4+2] + v.w * tg[k*CK + c4*4+3];
            }
            d *= tinv[k];
            if (d > best) { best = d; bk = k; }
        }
        #pragma unroll
        for (int k = 0; k < CTX; ++k) {
            unsigned long long mk = __ballot(bk == k);
            if (lane == 0) bmask[w][k] = mk;
        }
        __syncthreads();
        int pos = 0;
        for (int ww = 0; ww < w; ++ww) pos += __popcll(bmask[ww][bk]);
        pos += __popcll(bmask[w][bk] & ((1ull << lane) - 1ull));
        bucket_toks[((size_t)(b * CTX + bk)) * NMERGE + pos] = tok;
        if (j < CTX) {
            int c = 0;
            #pragma unroll
            for (int ww = 0; ww < 8; ++ww) c += __popcll(bmask[ww][j]);
            bucket_cnt[b * CTX + j] = c;
        }
    } else {
        __syncthreads();
    }
}

__global__ __launch_bounds__(256) void k_out(
    const float* __restrict__ hidden, const int* __restrict__ dom_idx,
    const int* __restrict__ rem_tok, const int* __restrict__ bucket_toks,
    const int* __restrict__ bucket_cnt, float* __restrict__ out)
{
    const int b = blockIdx.x / 65, r = blockIdx.x % 65;
    const int tid = threadIdx.x;
    float4* dst = (float4*)&out[((size_t)(b * 65 + r)) * D_];
    if (r < NSEL) {
        int tok = dom_idx[b * NSEL + r];
        dst[tid] = ((const float4*)&hidden[((size_t)(b * L_ + tok)) * D_])[tid];
    } else {
        const int k = r - NSEL;
        const int cnt = bucket_cnt[b * CTX + k];
        __shared__ int toks[NMERGE];
        for (int i = tid; i < cnt; i += 256)
            toks[i] = bucket_toks[((size_t)(b * CTX + k)) * NMERGE + i];
        __syncthreads();
        const float4* hb = (const float4*)&hidden[((size_t)b * L_) * D_];
        float4 a0 = make_float4(0,0,0,0), a1 = a0, a2 = a0, a3 = a0;
        int i = 0;
        for (; i + 4 <= cnt; i += 4) {
            float4 v0 = hb[(size_t)toks[i+0] * 256 + tid];
            float4 v1 = hb[(size_t)toks[i+1] * 256 + tid];
            float4 v2 = hb[(size_t)toks[i+2] * 256 + tid];
            float4 v3 = hb[(size_t)toks[i+3] * 256 + tid];
            a0.x += v0.x; a0.y += v0.y; a0.z += v0.z; a0.w += v0.w;
            a1.x += v1.x; a1.y += v1.y; a1.z += v1.z; a1.w += v1.w;
            a2.x += v2.x; a2.y += v2.y; a2.z += v2.z; a2.w += v2.w;
            a3.x += v3.x; a3.y += v3.y; a3.z += v3.z; a3.w += v3.w;
        }
        for (; i < cnt; ++i) {
            float4 v = hb[(size_t)toks[i] * 256 + tid];
            a0.x += v.x; a0.y += v.y; a0.z += v.z; a0.w += v.w;
        }
        float4 acc;
        acc.x = (a0.x + a1.x) + (a2.x + a3.x);
        acc.y = (a0.y + a1.y) + (a2.y + a3.y);
        acc.z = (a0.z + a1.z) + (a2.z + a3.z);
        acc.w = (a0.w + a1.w) + (a2.w + a3.w);
        const int tgt_tok = rem_tok[b * NR + 52 * k];
        float4 bv = hb[(size_t)tgt_tok * 256 + tid];
        float inv = 1.0f / fmaxf((float)cnt, 1.0f);
        float4 o;
        o.x = bv.x + acc.x * inv; o.y = bv.y + acc.y * inv;
        o.z = bv.z + acc.z * inv; o.w = bv.w + acc.w * inv;
        dst[tid] = o;
    }
}

extern "C" void kernel_launch(void* const* d_in, const int* in_sizes, int n_in,
                              void* d_out, int out_size, void* d_ws, size_t ws_size,
                              hipStream_t stream) {
    const float* attn   = (const float*)d_in[0];
    const float* hidden = (const float*)d_in[1];
    const float* metric = (const float*)d_in[2];
    const float* text   = (const float*)d_in[3];
    float* out = (float*)d_out;
    WS* ws = (WS*)d_ws;

    void* args[] = { (void*)&attn, (void*)&hidden, (void*)&metric,
                     (void*)&text, (void*)&out, (void*)&ws };
    hipError_t err = hipLaunchCooperativeKernel((const void*)fused, dim3(NBLK),
                                                dim3(NTHR), args, 0, stream);
    if (err != hipSuccess) {
        // fallback: proven 3-kernel path
        k_raw   <<<(B_ * LP) / 256, 256, 0, stream>>>(attn, metric, text,
                                                      ws->dot, ws->ss);
        k_select<<<B_, LP, 0, stream>>>(ws->dot, ws->ss, metric, ws->dom_idx,
                                        ws->rem_tok, ws->bucket_toks, ws->bucket_cnt);
        k_out   <<<B_ * 65, 256, 0, stream>>>(hidden, ws->dom_idx, ws->rem_tok,
                                              ws->bucket_toks, ws->bucket_cnt, out);
    }
}

// Round 6
// 72.093 us; speedup vs baseline: 3.6719x; 3.6719x over previous
//
#include <hip/hip_runtime.h>

#define B_   32
#define H_   16
#define L_   577
#define D_   1024
#define CK   64
#define LP   576    // L-1 patches
#define DOM  54
#define NSEL 55     // DOM + CLS
#define NR   522    // LP - DOM
#define CTX  10
#define NMERGE 512  // NR - CTX

// remain-list position for merge index m: p = m + min(m/51,9) + 1
__device__ __forceinline__ int remain_pos(int m) {
    int k = m / 51; if (k > 9) k = 9;
    return m + k + 1;
}

// block-wide sum over 576 threads (9 waves) — proven R1-R3
__device__ float block_sum576(float v) {
    __shared__ float red9[9];
    __shared__ float tot;
    for (int o = 32; o; o >>= 1) v += __shfl_xor(v, o);
    if ((threadIdx.x & 63) == 0) red9[threadIdx.x >> 6] = v;
    __syncthreads();
    if (threadIdx.x < 16) {
        float s = (threadIdx.x < 9) ? red9[threadIdx.x] : 0.f;
        for (int o = 8; o; o >>= 1) s += __shfl_xor(s, o);
        if (threadIdx.x == 0) tot = s;
    }
    __syncthreads();
    float r = tot;
    __syncthreads();
    return r;
}

// K0 (wide grid): raw per-patch scores Sd and cos — proven R3
__global__ __launch_bounds__(256) void k_raw(
    const float* __restrict__ attn, const float* __restrict__ metric,
    const float* __restrict__ text, float* __restrict__ Sd_arr,
    float* __restrict__ cos_arr)
{
    const int t = blockIdx.x * 256 + threadIdx.x;
    const int b = t / LP, j = t - b * LP;

    float Sd = 0.f;
    {
        size_t base = (size_t)b * H_ * L_ * L_ + (size_t)(1 + j);
        #pragma unroll
        for (int h = 0; h < H_; ++h) Sd += attn[base + (size_t)h * L_ * L_];
    }

    const float4* row  = (const float4*)&metric[((size_t)(b * L_ + 1 + j)) * CK];
    const float4* trow = (const float4*)&text[(size_t)b * CK];
    float dot = 0.f, ss = 0.f, ts = 0.f;
    #pragma unroll
    for (int c4 = 0; c4 < CK / 4; ++c4) {
        float4 v = row[c4]; float4 tv = trow[c4];
        ss  += v.x*v.x + v.y*v.y + v.z*v.z + v.w*v.w;
        ts  += tv.x*tv.x + tv.y*tv.y + tv.z*tv.z + tv.w*tv.w;
        dot += v.x*tv.x + v.y*tv.y + v.z*tv.z + v.w*tv.w;
    }
    Sd_arr[t]  = Sd;
    cos_arr[t] = dot / (sqrtf(ss) + 1e-12f) / (sqrtf(ts) + 1e-12f);
}

// K1: z-score + radix-select top-54 + lists + fused bucket assignment
__global__ __launch_bounds__(576) void k_select(
    const float* __restrict__ Sd_arr, const float* __restrict__ cos_arr,
    const float* __restrict__ metric,
    int* __restrict__ dom_idx, int* __restrict__ rem_tok,
    int* __restrict__ bucket_toks, int* __restrict__ bucket_cnt)
{
    const int b = blockIdx.x;
    const int j = threadIdx.x;       // patch index 0..575, token j+1
    const int w = j >> 6, lane = j & 63;

    __shared__ int   hist[256];
    __shared__ int   chosen_bin_sh;
    __shared__ int   rem_sh;
    __shared__ unsigned long long smask[9];
    __shared__ int   rem_s[NR];
    __shared__ float tg[CTX * CK];
    __shared__ float tinv[CTX];
    __shared__ unsigned long long bmask[8][CTX];

    // ---- z-scored combined score (ddof=1, eps on std) ----
    float Sd   = Sd_arr[b * LP + j];
    float cosv = cos_arr[b * LP + j];
    float mS = block_sum576(Sd)   * (1.f / LP);
    float dS = Sd - mS;
    float vS = block_sum576(dS * dS) * (1.f / (LP - 1));
    float mC = block_sum576(cosv) * (1.f / LP);
    float dC = cosv - mC;
    float vC = block_sum576(dC * dC) * (1.f / (LP - 1));
    float score = 0.5f * dS / (sqrtf(vS) + 1e-6f) + 0.5f * dC / (sqrtf(vC) + 1e-6f);

    // ---- radix select: top-54 with (score desc, index asc) tie-break ----
    // monotonic ascending key: larger key <=> larger score
    unsigned u = __float_as_uint(score);
    unsigned key = (u & 0x80000000u) ? ~u : (u | 0x80000000u);

    if (j == 0) rem_sh = DOM;
    bool cand = true, sel = false;
    #pragma unroll
    for (int d = 3; d >= 0; --d) {
        if (j < 256) hist[j] = 0;
        __syncthreads();
        int digit = (key >> (8 * d)) & 255;
        if (cand) atomicAdd(&hist[digit], 1);
        __syncthreads();
        if (j == 0) {
            int R = rem_sh, acc = 0, bsel = 0;
            for (int bb = 255; bb >= 0; --bb) {
                int h = hist[bb];
                if (acc + h >= R) { bsel = bb; break; }
                acc += h;
            }
            chosen_bin_sh = bsel;
            rem_sh = R - acc;              // still to take among digit==bsel
        }
        __syncthreads();
        int cb = chosen_bin_sh;
        if (cand) {
            if (digit > cb) sel = true;    // strictly above threshold digit: in
            cand = (digit == cb);
        }
    }
    // candidates now have key == K*; take first rem_sh by index (stable)
    {
        unsigned long long mc = __ballot(cand);
        if (lane == 0) smask[w] = mc;
        __syncthreads();
        int tpre = 0;
        for (int ww = 0; ww < w; ++ww) tpre += __popcll(smask[ww]);
        tpre += __popcll(smask[w] & ((1ull << lane) - 1ull));
        if (cand && tpre < rem_sh) sel = true;
        __syncthreads();   // before smask reuse
    }

    // ---- stable index compaction (ballot prefix) — proven R2/R3 ----
    {
        unsigned long long m = __ballot(sel);
        if (lane == 0) smask[w] = m;
        __syncthreads();
        int pre = 0;
        for (int ww = 0; ww < w; ++ww) pre += __popcll(smask[ww]);
        pre += __popcll(smask[w] & ((1ull << lane) - 1ull));
        if (j == 0) dom_idx[b * NSEL] = 0;
        if (sel) dom_idx[b * NSEL + 1 + pre] = j + 1;
        else { rem_s[j - pre] = j + 1; rem_tok[b * NR + (j - pre)] = j + 1; }
    }
    __syncthreads();

    // ---- stage 10 target rows + inv norms ----
    for (int i = j; i < CTX * CK; i += LP) {
        int k = i >> 6, c = i & 63;
        tg[i] = metric[((size_t)(b * L_ + rem_s[52 * k])) * CK + c];
    }
    __syncthreads();
    if (j < CTX) {
        float s2 = 0.f;
        for (int c = 0; c < CK; ++c) { float t = tg[j * CK + c]; s2 += t * t; }
        tinv[j] = 1.f / (sqrtf(s2) + 1e-12f);
    }
    __syncthreads();

    // ---- argmax assignment (merge-row norm dropped: argmax-invariant) ----
    if (j < NMERGE) {   // waves 0..7 active, wave 8 takes else (barrier-matched)
        const int tok = rem_s[remain_pos(j)];
        const float4* mrow = (const float4*)&metric[((size_t)(b * L_ + tok)) * CK];
        float4 r[16];
        #pragma unroll
        for (int c4 = 0; c4 < 16; ++c4) r[c4] = mrow[c4];
        float best = -1e30f; int bk = 0;
        #pragma unroll
        for (int k = 0; k < CTX; ++k) {
            float d = 0.f;
            #pragma unroll
            for (int c4 = 0; c4 < 16; ++c4) {
                float4 v = r[c4];
                d += v.x * tg[k*CK + c4*4+0] + v.y * tg[k*CK + c4*4+1] +
                     v.z * tg[k*CK + c4*4+2] + v.w * tg[k*CK + c4*4+3];
            }
            d *= tinv[k];
            if (d > best) { best = d; bk = k; }   // strict >: first max (jnp.argmax)
        }
        #pragma unroll
        for (int k = 0; k < CTX; ++k) {
            unsigned long long mk = __ballot(bk == k);
            if (lane == 0) bmask[w][k] = mk;
        }
        __syncthreads();
        int pos = 0;
        for (int ww = 0; ww < w; ++ww) pos += __popcll(bmask[ww][bk]);
        pos += __popcll(bmask[w][bk] & ((1ull << lane) - 1ull));
        bucket_toks[((size_t)(b * CTX + bk)) * NMERGE + pos] = tok;
        if (j < CTX) {
            int c = 0;
            #pragma unroll
            for (int ww = 0; ww < 8; ++ww) c += __popcll(bmask[ww][j]);
            bucket_cnt[b * CTX + j] = c;
        }
    } else {
        __syncthreads();
    }
}

// K2: contextual (heavy) blocks FIRST, dominant copies after
__global__ __launch_bounds__(256) void k_out(
    const float* __restrict__ hidden, const int* __restrict__ dom_idx,
    const int* __restrict__ rem_tok, const int* __restrict__ bucket_toks,
    const int* __restrict__ bucket_cnt, float* __restrict__ out)
{
    const int blk = blockIdx.x;
    const int tid = threadIdx.x;

    if (blk < B_ * CTX) {
        const int b = blk / CTX, k = blk % CTX;
        const int cnt = bucket_cnt[b * CTX + k];
        __shared__ int toks[NMERGE];
        for (int i = tid; i < cnt; i += 256)
            toks[i] = bucket_toks[((size_t)(b * CTX + k)) * NMERGE + i];
        __syncthreads();

        const float4* hb = (const float4*)&hidden[((size_t)b * L_) * D_];
        float4 a0 = make_float4(0,0,0,0), a1 = a0, a2 = a0, a3 = a0;
        float4 a4 = a0, a5 = a0, a6 = a0, a7 = a0;
        int i = 0;
        for (; i + 8 <= cnt; i += 8) {
            float4 v0 = hb[(size_t)toks[i+0] * 256 + tid];
            float4 v1 = hb[(size_t)toks[i+1] * 256 + tid];
            float4 v2 = hb[(size_t)toks[i+2] * 256 + tid];
            float4 v3 = hb[(size_t)toks[i+3] * 256 + tid];
            float4 v4 = hb[(size_t)toks[i+4] * 256 + tid];
            float4 v5 = hb[(size_t)toks[i+5] * 256 + tid];
            float4 v6 = hb[(size_t)toks[i+6] * 256 + tid];
            float4 v7 = hb[(size_t)toks[i+7] * 256 + tid];
            a0.x += v0.x; a0.y += v0.y; a0.z += v0.z; a0.w += v0.w;
            a1.x += v1.x; a1.y += v1.y; a1.z += v1.z; a1.w += v1.w;
            a2.x += v2.x; a2.y += v2.y; a2.z += v2.z; a2.w += v2.w;
            a3.x += v3.x; a3.y += v3.y; a3.z += v3.z; a3.w += v3.w;
            a4.x += v4.x; a4.y += v4.y; a4.z += v4.z; a4.w += v4.w;
            a5.x += v5.x; a5.y += v5.y; a5.z += v5.z; a5.w += v5.w;
            a6.x += v6.x; a6.y += v6.y; a6.z += v6.z; a6.w += v6.w;
            a7.x += v7.x; a7.y += v7.y; a7.z += v7.z; a7.w += v7.w;
        }
        for (; i < cnt; ++i) {
            float4 v = hb[(size_t)toks[i] * 256 + tid];
            a0.x += v.x; a0.y += v.y; a0.z += v.z; a0.w += v.w;
        }
        float4 acc;
        acc.x = ((a0.x + a1.x) + (a2.x + a3.x)) + ((a4.x + a5.x) + (a6.x + a7.x));
        acc.y = ((a0.y + a1.y) + (a2.y + a3.y)) + ((a4.y + a5.y) + (a6.y + a7.y));
        acc.z = ((a0.z + a1.z) + (a2.z + a3.z)) + ((a4.z + a5.z) + (a6.z + a7.z));
        acc.w = ((a0.w + a1.w) + (a2.w + a3.w)) + ((a4.w + a5.w) + (a6.w + a7.w));

        const int tgt_tok = rem_tok[b * NR + 52 * k];
        float4 bv = hb[(size_t)tgt_tok * 256 + tid];
        float inv = 1.0f / fmaxf((float)cnt, 1.0f);
        float4 o;
        o.x = bv.x + acc.x * inv; o.y = bv.y + acc.y * inv;
        o.z = bv.z + acc.z * inv; o.w = bv.w + acc.w * inv;
        ((float4*)&out[((size_t)(b * 65 + NSEL + k)) * D_])[tid] = o;
    } else {
        const int i2 = blk - B_ * CTX;
        const int b = i2 / NSEL, r = i2 % NSEL;
        int tok = dom_idx[b * NSEL + r];
        const float4* src = (const float4*)&hidden[((size_t)(b * L_ + tok)) * D_];
        ((float4*)&out[((size_t)(b * 65 + r)) * D_])[tid] = src[tid];
    }
}

extern "C" void kernel_launch(void* const* d_in, const int* in_sizes, int n_in,
                              void* d_out, int out_size, void* d_ws, size_t ws_size,
                              hipStream_t stream) {
    const float* attn   = (const float*)d_in[0];
    const float* hidden = (const float*)d_in[1];
    const float* metric = (const float*)d_in[2];
    const float* text   = (const float*)d_in[3];
    float* out = (float*)d_out;

    char* ws = (char*)d_ws;
    size_t off = 0;
    auto alloc = [&](size_t bytes) { void* p = ws + off; off = (off + bytes + 255) & ~(size_t)255; return p; };
    float* Sd_arr      = (float*)alloc((size_t)B_ * LP * 4);
    float* cos_arr     = (float*)alloc((size_t)B_ * LP * 4);
    int*   dom_idx     = (int*)  alloc((size_t)B_ * NSEL * 4);
    int*   rem_tok     = (int*)  alloc((size_t)B_ * NR * 4);
    int*   bucket_toks = (int*)  alloc((size_t)B_ * CTX * NMERGE * 4);
    int*   bucket_cnt  = (int*)  alloc((size_t)B_ * CTX * 4);

    k_raw   <<<(B_ * LP) / 256, 256, 0, stream>>>(attn, metric, text, Sd_arr, cos_arr);
    k_select<<<B_, LP, 0, stream>>>(Sd_arr, cos_arr, metric, dom_idx, rem_tok,
                                    bucket_toks, bucket_cnt);
    k_out   <<<B_ * 65, 256, 0, stream>>>(hidden, dom_idx, rem_tok, bucket_toks,
                                          bucket_cnt, out);
}

// Round 8
// 58.525 us; speedup vs baseline: 4.5232x; 1.2318x over previous
//
#include <hip/hip_runtime.h>

#define B_   32
#define H_   16
#define L_   577
#define D_   1024
#define CK   64
#define LP   576    // L-1 patches
#define DOM  54
#define NSEL 55     // DOM + CLS
#define NR   522    // LP - DOM
#define CTX  10
#define NMERGE 512  // NR - CTX
#define BL   (B_ * LP)

// remain-list position for merge index m: p = m + min(m/51,9) + 1
__device__ __forceinline__ int remain_pos(int m) {
    int k = m / 51; if (k > 9) k = 9;
    return m + k + 1;
}

// block-wide sum over 576 threads (9 waves) — proven R1-R3
__device__ float block_sum576(float v) {
    __shared__ float red9[9];
    __shared__ float tot;
    for (int o = 32; o; o >>= 1) v += __shfl_xor(v, o);
    if ((threadIdx.x & 63) == 0) red9[threadIdx.x >> 6] = v;
    __syncthreads();
    if (threadIdx.x < 16) {
        float s = (threadIdx.x < 9) ? red9[threadIdx.x] : 0.f;
        for (int o = 8; o; o >>= 1) s += __shfl_xor(s, o);
        if (threadIdx.x == 0) tot = s;
    }
    __syncthreads();
    float r = tot;
    __syncthreads();
    return r;
}

// K0 (truly wide): Sd head-group partials + per-wave cos scores
__global__ __launch_bounds__(256) void k_pre(
    const float* __restrict__ attn, const float* __restrict__ metric,
    const float* __restrict__ text, float* __restrict__ Sd_part,
    float* __restrict__ cos_arr)
{
    const int bid = blockIdx.x, tid = threadIdx.x;
    if (bid < 288) {
        // Sd partials: i indexes [q4][b*LP+j], thread sums heads 4q4..4q4+3
        int i = bid * 256 + tid;                  // [0, 4*BL)
        int q4 = i / BL, r = i - q4 * BL;
        int b = r / LP, j = r - b * LP;
        size_t base = ((size_t)b * H_ + 4 * q4) * L_ * L_ + 1 + j;
        const size_t LL = (size_t)L_ * L_;
        float s = (attn[base] + attn[base + LL]) +
                  (attn[base + 2 * LL] + attn[base + 3 * LL]);
        Sd_part[i] = s;
    } else {
        // cos: one wave per (b,j) — needs BL/4 = 4608 blocks after the 288
        int wid = (bid - 288) * 4 + (tid >> 6);   // [0, BL)
        int lane = tid & 63;
        int b = wid / LP, j = wid - b * LP;
        float m = metric[((size_t)(b * L_ + 1 + j)) * CK + lane];
        float t = text[b * CK + lane];
        float d = m * t, ss = m * m, ts = t * t;
        for (int o = 32; o; o >>= 1) {
            d += __shfl_xor(d, o); ss += __shfl_xor(ss, o); ts += __shfl_xor(ts, o);
        }
        if (lane == 0)
            cos_arr[wid] = d / (sqrtf(ss) + 1e-12f) / (sqrtf(ts) + 1e-12f);
    }
}

// K1: z-score + rank-loop top-54 (proven R3) + index lists
__global__ __launch_bounds__(576) void k_select(
    const float* __restrict__ Sd_part, const float* __restrict__ cos_arr,
    int* __restrict__ dom_idx, int* __restrict__ rem_tok)
{
    const int b = blockIdx.x;
    const int j = threadIdx.x;       // patch 0..575, token j+1
    const int w = j >> 6, lane = j & 63;

    __shared__ float sc[LP];
    __shared__ unsigned long long smask[9];

    const int idx = b * LP + j;
    float Sd = (Sd_part[idx] + Sd_part[BL + idx]) +
               (Sd_part[2 * BL + idx] + Sd_part[3 * BL + idx]);
    float cosv = cos_arr[idx];

    // z-scores (ddof=1, eps on std)
    float mS = block_sum576(Sd)   * (1.f / LP);
    float dS = Sd - mS;
    float vS = block_sum576(dS * dS) * (1.f / (LP - 1));
    float mC = block_sum576(cosv) * (1.f / LP);
    float dC = cosv - mC;
    float vC = block_sum576(dC * dC) * (1.f / (LP - 1));
    float score = 0.5f * dS / (sqrtf(vS) + 1e-6f) + 0.5f * dC / (sqrtf(vC) + 1e-6f);
    sc[j] = score;
    __syncthreads();

    // rank: LDS-broadcast loop (cheap), stable tie-break — exact top_k
    int rank = 0;
    for (int k = 0; k < LP; ++k) {
        float s = sc[k];
        rank += (s > score) || (s == score && k < j);
    }
    bool selj = (rank < DOM);

    unsigned long long m = __ballot(selj);
    if (lane == 0) smask[w] = m;
    __syncthreads();
    int pre = 0;
    for (int ww = 0; ww < w; ++ww) pre += __popcll(smask[ww]);
    pre += __popcll(smask[w] & ((1ull << lane) - 1ull));

    if (j == 0) dom_idx[b * NSEL] = 0;
    if (selj) dom_idx[b * NSEL + 1 + pre] = j + 1;
    else      rem_tok[b * NR + (j - pre)] = j + 1;
}

// K2 (wide): argmax assignment; writes packed (tok<<4)|bucket
__global__ __launch_bounds__(128) void k_assign(
    const float* __restrict__ metric, const int* __restrict__ rem_tok,
    int* __restrict__ assign_tok)
{
    const int b = blockIdx.x >> 2, qtr = blockIdx.x & 3;
    const int tid = threadIdx.x;
    __shared__ float tg[CTX * CK];
    __shared__ float tinv[CTX];

    for (int i = tid; i < CTX * CK; i += 128) {
        int kk = i >> 6, c = i & 63;
        int t10 = rem_tok[b * NR + 52 * kk];
        tg[i] = metric[((size_t)(b * L_ + t10)) * CK + c];
    }
    __syncthreads();
    if (tid < CTX) {
        float s2 = 0.f;
        for (int c = 0; c < CK; ++c) { float t = tg[tid * CK + c]; s2 += t * t; }
        tinv[tid] = 1.f / (sqrtf(s2) + 1e-12f);
    }
    __syncthreads();

    const int m = qtr * 128 + tid;
    const int tok = rem_tok[b * NR + remain_pos(m)];
    const float4* row = (const float4*)&metric[((size_t)(b * L_ + tok)) * CK];
    float4 r[16];
    #pragma unroll
    for (int c4 = 0; c4 < 16; ++c4) r[c4] = row[c4];

    // merge-row norm dropped: positive scalar, argmax-invariant
    float best = -1e30f; int bk = 0;
    #pragma unroll
    for (int k = 0; k < CTX; ++k) {
        float d = 0.f;
        #pragma unroll
        for (int c4 = 0; c4 < 16; ++c4) {
            float4 v = r[c4];
            d += v.x * tg[k*CK + c4*4+0] + v.y * tg[k*CK + c4*4+1] +
                 v.z * tg[k*CK + c4*4+2] + v.w * tg[k*CK + c4*4+3];
        }
        d *= tinv[k];
        if (d > best) { best = d; bk = k; }   // strict >: first max (jnp.argmax)
    }
    assign_tok[b * NMERGE + m] = (tok << 4) | bk;
}

// K3: heavy (contextual) blocks first; in-block bucket-list build + gather
__global__ __launch_bounds__(256) void k_out(
    const float* __restrict__ hidden, const int* __restrict__ dom_idx,
    const int* __restrict__ rem_tok, const int* __restrict__ assign_tok,
    float* __restrict__ out)
{
    const int blk = blockIdx.x;
    const int tid = threadIdx.x;

    if (blk < B_ * CTX) {
        const int b = blk / CTX, k = blk % CTX;
        const int w = tid >> 6, lane = tid & 63;
        __shared__ int at[NMERGE];
        __shared__ int toks[NMERGE];
        __shared__ unsigned long long cmask[2][4];

        at[tid]       = assign_tok[b * NMERGE + tid];
        at[tid + 256] = assign_tok[b * NMERGE + tid + 256];
        __syncthreads();
        int a0 = at[tid], a1 = at[tid + 256];
        bool m0 = (a0 & 15) == k, m1 = (a1 & 15) == k;
        unsigned long long bl0 = __ballot(m0), bl1 = __ballot(m1);
        if (lane == 0) { cmask[0][w] = bl0; cmask[1][w] = bl1; }
        __syncthreads();
        int sum0 = 0, pre0 = 0, pre1 = 0;
        #pragma unroll
        for (int ww = 0; ww < 4; ++ww) {
            int p0 = __popcll(cmask[0][ww]);
            sum0 += p0;
            if (ww < w) { pre0 += p0; pre1 += __popcll(cmask[1][ww]); }
        }
        int sum1 = 0;
        #pragma unroll
        for (int ww = 0; ww < 4; ++ww) sum1 += __popcll(cmask[1][ww]);
        unsigned long long lt = (1ull << lane) - 1ull;
        if (m0) toks[pre0 + __popcll(bl0 & lt)] = a0 >> 4;
        if (m1) toks[sum0 + pre1 + __popcll(bl1 & lt)] = a1 >> 4;
        const int cnt = sum0 + sum1;
        __syncthreads();

        const float4* hb = (const float4*)&hidden[((size_t)b * L_) * D_];
        float4 a_0 = make_float4(0,0,0,0), a_1 = a_0, a_2 = a_0, a_3 = a_0;
        float4 a_4 = a_0, a_5 = a_0, a_6 = a_0, a_7 = a_0;
        int i = 0;
        for (; i + 8 <= cnt; i += 8) {
            float4 v0 = hb[(size_t)toks[i+0] * 256 + tid];
            float4 v1 = hb[(size_t)toks[i+1] * 256 + tid];
            float4 v2 = hb[(size_t)toks[i+2] * 256 + tid];
            float4 v3 = hb[(size_t)toks[i+3] * 256 + tid];
            float4 v4 = hb[(size_t)toks[i+4] * 256 + tid];
            float4 v5 = hb[(size_t)toks[i+5] * 256 + tid];
            float4 v6 = hb[(size_t)toks[i+6] * 256 + tid];
            float4 v7 = hb[(size_t)toks[i+7] * 256 + tid];
            a_0.x += v0.x; a_0.y += v0.y; a_0.z += v0.z; a_0.w += v0.w;
            a_1.x += v1.x; a_1.y += v1.y; a_1.z += v1.z; a_1.w += v1.w;
            a_2.x += v2.x; a_2.y += v2.y; a_2.z += v2.z; a_2.w += v2.w;
            a_3.x += v3.x; a_3.y += v3.y; a_3.z += v3.z; a_3.w += v3.w;
            a_4.x += v4.x; a_4.y += v4.y; a_4.z += v4.z; a_4.w += v4.w;
            a_5.x += v5.x; a_5.y += v5.y; a_5.z += v5.z; a_5.w += v5.w;
            a_6.x += v6.x; a_6.y += v6.y; a_6.z += v6.z; a_6.w += v6.w;
            a_7.x += v7.x; a_7.y += v7.y; a_7.z += v7.z; a_7.w += v7.w;
        }
        for (; i < cnt; ++i) {
            float4 v = hb[(size_t)toks[i] * 256 + tid];
            a_0.x += v.x; a_0.y += v.y; a_0.z += v.z; a_0.w += v.w;
        }
        float4 acc;
        acc.x = ((a_0.x + a_1.x) + (a_2.x + a_3.x)) + ((a_4.x + a_5.x) + (a_6.x + a_7.x));
        acc.y = ((a_0.y + a_1.y) + (a_2.y + a_3.y)) + ((a_4.y + a_5.y) + (a_6.y + a_7.y));
        acc.z = ((a_0.z + a_1.z) + (a_2.z + a_3.z)) + ((a_4.z + a_5.z) + (a_6.z + a_7.z));
        acc.w = ((a_0.w + a_1.w) + (a_2.w + a_3.w)) + ((a_4.w + a_5.w) + (a_6.w + a_7.w));

        const int tgt_tok = rem_tok[b * NR + 52 * k];
        float4 bv = hb[(size_t)tgt_tok * 256 + tid];
        float inv = 1.0f / fmaxf((float)cnt, 1.0f);
        float4 o;
        o.x = bv.x + acc.x * inv; o.y = bv.y + acc.y * inv;
        o.z = bv.z + acc.z * inv; o.w = bv.w + acc.w * inv;
        ((float4*)&out[((size_t)(b * 65 + NSEL + k)) * D_])[tid] = o;
    } else {
        const int i2 = blk - B_ * CTX;
        const int b = i2 / NSEL, r = i2 % NSEL;
        int tok = dom_idx[b * NSEL + r];
        const float4* src = (const float4*)&hidden[((size_t)(b * L_ + tok)) * D_];
        ((float4*)&out[((size_t)(b * 65 + r)) * D_])[tid] = src[tid];
    }
}

extern "C" void kernel_launch(void* const* d_in, const int* in_sizes, int n_in,
                              void* d_out, int out_size, void* d_ws, size_t ws_size,
                              hipStream_t stream) {
    const float* attn   = (const float*)d_in[0];
    const float* hidden = (const float*)d_in[1];
    const float* metric = (const float*)d_in[2];
    const float* text   = (const float*)d_in[3];
    float* out = (float*)d_out;

    char* ws = (char*)d_ws;
    size_t off = 0;
    auto alloc = [&](size_t bytes) { void* p = ws + off; off = (off + bytes + 255) & ~(size_t)255; return p; };
    float* Sd_part    = (float*)alloc((size_t)4 * BL * 4);
    float* cos_arr    = (float*)alloc((size_t)BL * 4);
    int*   dom_idx    = (int*)  alloc((size_t)B_ * NSEL * 4);
    int*   rem_tok    = (int*)  alloc((size_t)B_ * NR * 4);
    int*   assign_tok = (int*)  alloc((size_t)B_ * NMERGE * 4);

    // 288 Sd-partial blocks + BL/4 = 4608 cos blocks (one wave per (b,j))
    k_pre   <<<288 + BL / 4, 256, 0, stream>>>(attn, metric, text, Sd_part, cos_arr);
    k_select<<<B_, LP, 0, stream>>>(Sd_part, cos_arr, dom_idx, rem_tok);
    k_assign<<<B_ * 4, 128, 0, stream>>>(metric, rem_tok, assign_tok);
    k_out   <<<B_ * 65, 256, 0, stream>>>(hidden, dom_idx, rem_tok, assign_tok, out);
}